// Round 6
// baseline (720.916 us; speedup 1.0000x reference)
//
#include <hip/hip_runtime.h>
#include <hip/hip_cooperative_groups.h>
#include <cstdint>
#include <cstddef>

namespace cg = cooperative_groups;

typedef unsigned short u16;
typedef __bf16 bf16x8 __attribute__((ext_vector_type(8)));
typedef u16 u16x8 __attribute__((ext_vector_type(8)));
typedef float f32x4 __attribute__((ext_vector_type(4)));

#define N_NODES 100000
#define SAMPLE 25
#define FEAT 128
#define CLASSES 40

__device__ __forceinline__ float bf2f(u16 v) {
    return __uint_as_float(((unsigned)v) << 16);
}
__device__ __forceinline__ u16 f2bf(float f) {
    unsigned u = __float_as_uint(f);
    u += 0x7FFFu + ((u >> 16) & 1u);
    return (u16)(u >> 16);
}
__device__ __forceinline__ void split_bf(float x, u16& hi, u16& lo) {
    hi = f2bf(x);
    lo = f2bf(x - bf2f(hi));
}

__device__ __forceinline__ void split8(const float* ap, bf16x8& ah, bf16x8& al) {
    union { u16x8 u; bf16x8 b; } H, L;
    #pragma unroll
    for (int j = 0; j < 8; ++j) {
        u16 h, lo; split_bf(ap[j], h, lo);
        H.u[j] = h; L.u[j] = lo;
    }
    ah = H.b; al = L.b;
}

__device__ __forceinline__ f32x4 mfma_split(bf16x8 ah, bf16x8 al,
                                            bf16x8 bh, bf16x8 bl, f32x4 acc) {
    acc = __builtin_amdgcn_mfma_f32_16x16x32_bf16(ah, bh, acc, 0, 0, 0);
    acc = __builtin_amdgcn_mfma_f32_16x16x32_bf16(al, bh, acc, 0, 0, 0);
    acc = __builtin_amdgcn_mfma_f32_16x16x32_bf16(ah, bl, acc, 0, 0, 0);
    return acc;
}

#define NPB32 32
#define ZT_STRIDE 136
#define NGROUPS 3125           // N_NODES / NPB32

// ===========================================================================
// FUSED COOPERATIVE KERNEL: prep -> gridsync -> hopA -> gridsync -> hopB
// Work-stealing via global atomic counters (ctr[0]: hopA groups, ctr[1]: hopB).
// Phase bodies == R5's proven kernels. LDS aliased across phases (20.6 KB).
// __launch_bounds__(128,3): 2nd arg is waves/EU -> 6 blocks/CU, VGPR cap 84
// (R4 lesson: hopA/hopB bodies use ~60 VGPR, no spill at this cap).
// ===========================================================================
__global__ __launch_bounds__(128, 3) void fused_all(
    const float* __restrict__ X, const int* __restrict__ nb,
    const float* __restrict__ W1, const float* __restrict__ W2,
    const float* __restrict__ Wl,
    u16* __restrict__ Xb, u16* __restrict__ Z2,
    u16* __restrict__ w1h, u16* __restrict__ w1l,
    u16* __restrict__ w2h, u16* __restrict__ w2l,
    u16* __restrict__ wlh, u16* __restrict__ wll,
    int* __restrict__ ctr,
    float* __restrict__ out)
{
    __shared__ int nbs[NPB32 * SAMPLE];                   // 3200 B
    __shared__ __align__(16) char smembig[2 * NPB32 * ZT_STRIDE * 2]; // 17408 B
    u16 (*agg_h)[ZT_STRIDE] = (u16(*)[ZT_STRIDE])smembig;
    u16 (*agg_l)[ZT_STRIDE] = (u16(*)[ZT_STRIDE])(smembig + NPB32 * ZT_STRIDE * 2);
    float (*aggf)[132] = (float(*)[132])smembig;          // phase-B view (16896 B)
    __shared__ int g_sh;

    const int t = threadIdx.x;
    cg::grid_group grid = cg::this_grid();

    // ---------------- phase 0: prep (grid-stride) ----------------
    {
        if (blockIdx.x == 0 && t == 0) { ctr[0] = 0; ctr[1] = 0; }
        const int i = blockIdx.x * 128 + t;
        const int stride = gridDim.x * 128;
        const int nv = (N_NODES * FEAT) / 8;
        for (int v = i; v < nv; v += stride) {
            f32x4 a = *(const f32x4*)(X + (size_t)v * 8);
            f32x4 b = *(const f32x4*)(X + (size_t)v * 8 + 4);
            u16x8 o;
            o[0] = f2bf(a[0]); o[1] = f2bf(a[1]); o[2] = f2bf(a[2]); o[3] = f2bf(a[3]);
            o[4] = f2bf(b[0]); o[5] = f2bf(b[1]); o[6] = f2bf(b[2]); o[7] = f2bf(b[3]);
            *(u16x8*)(Xb + (size_t)v * 8) = o;
        }
        for (int j = i; j < FEAT * FEAT; j += stride) {
            split_bf(W1[j], w1h[j], w1l[j]);
            split_bf(W2[j], w2h[j], w2l[j]);
        }
        for (int j = i; j < CLASSES * FEAT; j += stride) {
            split_bf(Wl[j], wlh[j], wll[j]);
        }
    }
    grid.sync();

    // ---------------- phase A: hopA (work-stealing over 3125 groups) --------
    const int w  = t >> 6;
    const int l  = t & 63;
    const int lr = l & 15;
    const int lq = l >> 4;

    for (;;) {
        __syncthreads();                    // prev body fully done with LDS
        if (t == 0) g_sh = atomicAdd(&ctr[0], 1);
        __syncthreads();
        const int gid = g_sh;
        if (gid >= NGROUPS) break;          // uniform
        const int blockStart = gid * NPB32;

        for (int i = t; i < NPB32 * SAMPLE; i += 128)
            nbs[i] = nb[blockStart * SAMPLE + i];
        __syncthreads();

        // gather: burst 25 bf16 rows into registers, accumulate f32
        #pragma unroll 1
        for (int it = 0; it < 4; ++it) {
            const int item = t + it * 128;
            const int nl = item >> 4;
            const int fg = item & 15;
            const int* myn = &nbs[nl * SAMPLE];
            u16x8 buf[SAMPLE];
            #pragma unroll
            for (int s = 0; s < SAMPLE; ++s)
                buf[s] = *(const u16x8*)(Xb + ((size_t)myn[s] << 7) + fg * 8);
            float acc[8];
            #pragma unroll
            for (int j = 0; j < 8; ++j) acc[j] = 0.f;
            #pragma unroll
            for (int s = 0; s < SAMPLE; ++s) {
                #pragma unroll
                for (int j = 0; j < 8; ++j) acc[j] += bf2f(buf[s][j]);
            }
            u16x8 oh, ol;
            #pragma unroll
            for (int j = 0; j < 8; ++j) {
                const float m = acc[j] * (1.0f / SAMPLE);   // mean, NO relu
                u16 h, lo; split_bf(m, h, lo);
                oh[j] = h; ol[j] = lo;
            }
            *(u16x8*)&agg_h[nl][fg * 8] = oh;
            *(u16x8*)&agg_l[nl][fg * 8] = ol;
        }
        __syncthreads();

        // GEMM1: hacc = agg @ W1^T
        f32x4 hacc[8];
        {
            bf16x8 ah[4], al[4];
            #pragma unroll
            for (int k = 0; k < 4; ++k) {
                ah[k] = *(const bf16x8*)&agg_h[w * 16 + lr][k * 32 + lq * 8];
                al[k] = *(const bf16x8*)&agg_l[w * 16 + lr][k * 32 + lq * 8];
            }
            #pragma unroll
            for (int c = 0; c < 8; ++c) {
                f32x4 acc = {0.f, 0.f, 0.f, 0.f};
                #pragma unroll
                for (int k = 0; k < 4; ++k) {
                    const size_t off = (size_t)(c * 16 + lr) * FEAT + k * 32 + lq * 8;
                    bf16x8 bh = *(const bf16x8*)(w1h + off);
                    bf16x8 bl = *(const bf16x8*)(w1l + off);
                    acc = mfma_split(ah[k], al[k], bh, bl, acc);
                }
                hacc[c] = acc;
            }
        }
        __syncthreads();

        // relu + hi/lo split back into LDS
        #pragma unroll
        for (int c = 0; c < 8; ++c) {
            #pragma unroll
            for (int r = 0; r < 4; ++r) {
                float v = hacc[c][r] > 0.f ? hacc[c][r] : 0.f;
                u16 h, l2; split_bf(v, h, l2);
                agg_h[w * 16 + lq * 4 + r][c * 16 + lr] = h;
                agg_l[w * 16 + lq * 4 + r][c * 16 + lr] = l2;
            }
        }
        __syncthreads();

        // GEMM2: Z2 = h1 @ W2^T (no relu), bf16 staged in agg_h
        {
            bf16x8 ah[4], al[4];
            #pragma unroll
            for (int k = 0; k < 4; ++k) {
                ah[k] = *(const bf16x8*)&agg_h[w * 16 + lr][k * 32 + lq * 8];
                al[k] = *(const bf16x8*)&agg_l[w * 16 + lr][k * 32 + lq * 8];
            }
            __syncthreads();               // A-frags in regs; agg_h reusable

            #pragma unroll
            for (int c = 0; c < 8; ++c) {
                f32x4 acc = {0.f, 0.f, 0.f, 0.f};
                #pragma unroll
                for (int k = 0; k < 4; ++k) {
                    const size_t off = (size_t)(c * 16 + lr) * FEAT + k * 32 + lq * 8;
                    bf16x8 bh = *(const bf16x8*)(w2h + off);
                    bf16x8 bl = *(const bf16x8*)(w2l + off);
                    acc = mfma_split(ah[k], al[k], bh, bl, acc);
                }
                #pragma unroll
                for (int r = 0; r < 4; ++r)
                    agg_h[w * 16 + lq * 4 + r][c * 16 + lr] = f2bf(acc[r]);
            }
        }
        __syncthreads();

        #pragma unroll
        for (int p = 0; p < 4; ++p) {
            const int idx = p * 128 + t;
            const int row = idx >> 4;
            const int col = (idx & 15) * 8;
            *(u16x8*)(Z2 + (size_t)(blockStart + row) * FEAT + col) =
                *(const u16x8*)&agg_h[row][col];
        }
    }
    grid.sync();

    // ---------------- phase B: hopB (work-stealing over 3125 groups) --------
    for (;;) {
        __syncthreads();
        if (t == 0) g_sh = atomicAdd(&ctr[1], 1);
        __syncthreads();
        const int gid = g_sh;
        if (gid >= NGROUPS) break;
        const int blockStart = gid * NPB32;

        for (int i = t; i < NPB32 * SAMPLE; i += 128)
            nbs[i] = nb[blockStart * SAMPLE + i];
        __syncthreads();

        #pragma unroll 1
        for (int it = 0; it < 4; ++it) {
            const int item = t + it * 128;
            const int nl = item >> 4;
            const int fg = item & 15;
            const int* myn = &nbs[nl * SAMPLE];
            u16x8 buf[SAMPLE];
            #pragma unroll
            for (int s = 0; s < SAMPLE; ++s)
                buf[s] = *(const u16x8*)(Z2 + ((size_t)myn[s] << 7) + fg * 8);
            float acc[8];
            #pragma unroll
            for (int j = 0; j < 8; ++j) acc[j] = 0.f;
            #pragma unroll
            for (int s = 0; s < SAMPLE; ++s) {
                #pragma unroll
                for (int j = 0; j < 8; ++j) acc[j] += bf2f(buf[s][j]);
            }
            #pragma unroll
            for (int j = 0; j < 8; ++j) {
                float m = acc[j] * (1.0f / SAMPLE);
                aggf[nl][fg * 8 + j] = m > 0.f ? m : 0.f;   // relu(mean)
            }
        }
        __syncthreads();

        bf16x8 ah[4], al[4];
        #pragma unroll
        for (int k = 0; k < 4; ++k)
            split8(&aggf[w * 16 + lr][k * 32 + lq * 8], ah[k], al[k]);

        #pragma unroll
        for (int c = 0; c < 3; ++c) {
            const int o = c * 16 + lr;
            f32x4 acc = {0.f, 0.f, 0.f, 0.f};
            #pragma unroll
            for (int k = 0; k < 4; ++k) {
                bf16x8 bh, bl;
                if (o < CLASSES) {
                    const size_t off = (size_t)o * FEAT + k * 32 + lq * 8;
                    bh = *(const bf16x8*)(wlh + off);
                    bl = *(const bf16x8*)(wll + off);
                } else {
                    #pragma unroll
                    for (int j = 0; j < 8; ++j) { bh[j] = (__bf16)0.f; bl[j] = (__bf16)0.f; }
                }
                acc = mfma_split(ah[k], al[k], bh, bl, acc);
            }
            if (o < CLASSES) {
                #pragma unroll
                for (int r = 0; r < 4; ++r) {
                    const int node = blockStart + w * 16 + lq * 4 + r;
                    out[(size_t)node * CLASSES + o] = acc[r];
                }
            }
        }
    }
}

// ===========================================================================
// NON-COOPERATIVE FALLBACK (R5's proven 3-kernel fast path)
// ===========================================================================
__global__ __launch_bounds__(256) void prep_all(
    const float* __restrict__ X,
    const float* __restrict__ W1, const float* __restrict__ W2,
    const float* __restrict__ Wl,
    u16* __restrict__ xb,
    u16* __restrict__ w1h, u16* __restrict__ w1l,
    u16* __restrict__ w2h, u16* __restrict__ w2l,
    u16* __restrict__ wlh, u16* __restrict__ wll)
{
    const int i = blockIdx.x * 256 + threadIdx.x;
    const int stride = gridDim.x * 256;

    const int nv = (N_NODES * FEAT) / 8;
    for (int v = i; v < nv; v += stride) {
        f32x4 a = *(const f32x4*)(X + (size_t)v * 8);
        f32x4 b = *(const f32x4*)(X + (size_t)v * 8 + 4);
        u16x8 o;
        o[0] = f2bf(a[0]); o[1] = f2bf(a[1]); o[2] = f2bf(a[2]); o[3] = f2bf(a[3]);
        o[4] = f2bf(b[0]); o[5] = f2bf(b[1]); o[6] = f2bf(b[2]); o[7] = f2bf(b[3]);
        *(u16x8*)(xb + (size_t)v * 8) = o;
    }
    for (int j = i; j < FEAT * FEAT; j += stride) {
        split_bf(W1[j], w1h[j], w1l[j]);
        split_bf(W2[j], w2h[j], w2l[j]);
    }
    for (int j = i; j < CLASSES * FEAT; j += stride) {
        split_bf(Wl[j], wlh[j], wll[j]);
    }
}

__global__ __launch_bounds__(128, 2) void hopA(
    const u16* __restrict__ Xb, const int* __restrict__ nb,
    const u16* __restrict__ w1h, const u16* __restrict__ w1l,
    const u16* __restrict__ w2h, const u16* __restrict__ w2l,
    u16* __restrict__ Z2)
{
    __shared__ int nbs[NPB32 * SAMPLE];
    __shared__ u16 agg_h[NPB32][ZT_STRIDE];
    __shared__ u16 agg_l[NPB32][ZT_STRIDE];

    const int t = threadIdx.x;
    const int blockStart = blockIdx.x * NPB32;

    for (int i = t; i < NPB32 * SAMPLE; i += 128)
        nbs[i] = nb[blockStart * SAMPLE + i];
    __syncthreads();

    #pragma unroll 1
    for (int it = 0; it < 4; ++it) {
        const int item = t + it * 128;
        const int nl = item >> 4;
        const int fg = item & 15;
        const int* myn = &nbs[nl * SAMPLE];
        u16x8 buf[SAMPLE];
        #pragma unroll
        for (int s = 0; s < SAMPLE; ++s)
            buf[s] = *(const u16x8*)(Xb + ((size_t)myn[s] << 7) + fg * 8);
        float acc[8];
        #pragma unroll
        for (int j = 0; j < 8; ++j) acc[j] = 0.f;
        #pragma unroll
        for (int s = 0; s < SAMPLE; ++s) {
            #pragma unroll
            for (int j = 0; j < 8; ++j) acc[j] += bf2f(buf[s][j]);
        }
        u16x8 oh, ol;
        #pragma unroll
        for (int j = 0; j < 8; ++j) {
            const float m = acc[j] * (1.0f / SAMPLE);
            u16 h, lo; split_bf(m, h, lo);
            oh[j] = h; ol[j] = lo;
        }
        *(u16x8*)&agg_h[nl][fg * 8] = oh;
        *(u16x8*)&agg_l[nl][fg * 8] = ol;
    }
    __syncthreads();

    const int w  = t >> 6;
    const int l  = t & 63;
    const int lr = l & 15;
    const int lq = l >> 4;

    f32x4 hacc[8];
    {
        bf16x8 ah[4], al[4];
        #pragma unroll
        for (int k = 0; k < 4; ++k) {
            ah[k] = *(const bf16x8*)&agg_h[w * 16 + lr][k * 32 + lq * 8];
            al[k] = *(const bf16x8*)&agg_l[w * 16 + lr][k * 32 + lq * 8];
        }
        #pragma unroll
        for (int c = 0; c < 8; ++c) {
            f32x4 acc = {0.f, 0.f, 0.f, 0.f};
            #pragma unroll
            for (int k = 0; k < 4; ++k) {
                const size_t off = (size_t)(c * 16 + lr) * FEAT + k * 32 + lq * 8;
                bf16x8 bh = *(const bf16x8*)(w1h + off);
                bf16x8 bl = *(const bf16x8*)(w1l + off);
                acc = mfma_split(ah[k], al[k], bh, bl, acc);
            }
            hacc[c] = acc;
        }
    }
    __syncthreads();

    #pragma unroll
    for (int c = 0; c < 8; ++c) {
        #pragma unroll
        for (int r = 0; r < 4; ++r) {
            float v = hacc[c][r] > 0.f ? hacc[c][r] : 0.f;
            u16 h, l2; split_bf(v, h, l2);
            agg_h[w * 16 + lq * 4 + r][c * 16 + lr] = h;
            agg_l[w * 16 + lq * 4 + r][c * 16 + lr] = l2;
        }
    }
    __syncthreads();

    {
        bf16x8 ah[4], al[4];
        #pragma unroll
        for (int k = 0; k < 4; ++k) {
            ah[k] = *(const bf16x8*)&agg_h[w * 16 + lr][k * 32 + lq * 8];
            al[k] = *(const bf16x8*)&agg_l[w * 16 + lr][k * 32 + lq * 8];
        }
        __syncthreads();

        #pragma unroll
        for (int c = 0; c < 8; ++c) {
            f32x4 acc = {0.f, 0.f, 0.f, 0.f};
            #pragma unroll
            for (int k = 0; k < 4; ++k) {
                const size_t off = (size_t)(c * 16 + lr) * FEAT + k * 32 + lq * 8;
                bf16x8 bh = *(const bf16x8*)(w2h + off);
                bf16x8 bl = *(const bf16x8*)(w2l + off);
                acc = mfma_split(ah[k], al[k], bh, bl, acc);
            }
            #pragma unroll
            for (int r = 0; r < 4; ++r)
                agg_h[w * 16 + lq * 4 + r][c * 16 + lr] = f2bf(acc[r]);
        }
    }
    __syncthreads();

    #pragma unroll
    for (int p = 0; p < 4; ++p) {
        const int idx = p * 128 + t;
        const int row = idx >> 4;
        const int col = (idx & 15) * 8;
        *(u16x8*)(Z2 + (size_t)(blockStart + row) * FEAT + col) =
            *(const u16x8*)&agg_h[row][col];
    }
}

__global__ __launch_bounds__(128, 3) void hopB(
    const u16* __restrict__ Zin, const int* __restrict__ nb,
    const u16* __restrict__ wh, const u16* __restrict__ wl,
    float* __restrict__ out)
{
    __shared__ int nbs[NPB32 * SAMPLE];
    __shared__ float agg[NPB32][132];

    const int t = threadIdx.x;
    const int blockStart = blockIdx.x * NPB32;

    for (int i = t; i < NPB32 * SAMPLE; i += 128)
        nbs[i] = nb[blockStart * SAMPLE + i];
    __syncthreads();

    #pragma unroll 1
    for (int it = 0; it < 4; ++it) {
        const int item = t + it * 128;
        const int nl = item >> 4;
        const int fg = item & 15;
        const int* myn = &nbs[nl * SAMPLE];
        u16x8 buf[SAMPLE];
        #pragma unroll
        for (int s = 0; s < SAMPLE; ++s)
            buf[s] = *(const u16x8*)(Zin + ((size_t)myn[s] << 7) + fg * 8);
        float acc[8];
        #pragma unroll
        for (int j = 0; j < 8; ++j) acc[j] = 0.f;
        #pragma unroll
        for (int s = 0; s < SAMPLE; ++s) {
            #pragma unroll
            for (int j = 0; j < 8; ++j) acc[j] += bf2f(buf[s][j]);
        }
        #pragma unroll
        for (int j = 0; j < 8; ++j) {
            float m = acc[j] * (1.0f / SAMPLE);
            agg[nl][fg * 8 + j] = m > 0.f ? m : 0.f;
        }
    }
    __syncthreads();

    const int w  = t >> 6;
    const int l  = t & 63;
    const int lr = l & 15;
    const int lq = l >> 4;

    bf16x8 ah[4], al[4];
    #pragma unroll
    for (int k = 0; k < 4; ++k)
        split8(&agg[w * 16 + lr][k * 32 + lq * 8], ah[k], al[k]);

    #pragma unroll
    for (int c = 0; c < 3; ++c) {
        const int o = c * 16 + lr;
        f32x4 acc = {0.f, 0.f, 0.f, 0.f};
        #pragma unroll
        for (int k = 0; k < 4; ++k) {
            bf16x8 bh, bl;
            if (o < CLASSES) {
                const size_t off = (size_t)o * FEAT + k * 32 + lq * 8;
                bh = *(const bf16x8*)(wh + off);
                bl = *(const bf16x8*)(wl + off);
            } else {
                #pragma unroll
                for (int j = 0; j < 8; ++j) { bh[j] = (__bf16)0.f; bl[j] = (__bf16)0.f; }
            }
            acc = mfma_split(ah[k], al[k], bh, bl, acc);
        }
        if (o < CLASSES) {
            #pragma unroll
            for (int r = 0; r < 4; ++r) {
                const int node = blockStart + w * 16 + lq * 4 + r;
                out[(size_t)node * CLASSES + o] = acc[r];
            }
        }
    }
}

// ===========================================================================
// FALLBACK PATH (small ws)
// ===========================================================================
#define NPB 64
#define AGG_STRIDE 136

__global__ __launch_bounds__(256) void gnn_layer1(
    const float* __restrict__ X, const int* __restrict__ nb,
    const u16* __restrict__ w1h, const u16* __restrict__ w1l,
    u16* __restrict__ h1)
{
    __shared__ int nbs[NPB * SAMPLE];
    __shared__ u16 agg_h[NPB][AGG_STRIDE];
    __shared__ u16 agg_l[NPB][AGG_STRIDE];

    const int t = threadIdx.x;
    const int blockStart = blockIdx.x * NPB;

    for (int i = t; i < NPB * SAMPLE; i += 256) {
        int gi = blockStart * SAMPLE + i;
        if (gi >= N_NODES * SAMPLE) gi = N_NODES * SAMPLE - 1;
        nbs[i] = nb[gi];
    }
    __syncthreads();

    for (int item = t; item < NPB * 16; item += 256) {
        const int nl = item >> 4;
        const int fg = item & 15;
        float acc[8];
        #pragma unroll
        for (int j = 0; j < 8; ++j) acc[j] = 0.f;
        const int* myn = &nbs[nl * SAMPLE];
        for (int s = 0; s < SAMPLE; ++s) {
            const float4* p = (const float4*)(X + (size_t)myn[s] * FEAT + fg * 8);
            float4 a = p[0], b = p[1];
            acc[0] += a.x; acc[1] += a.y; acc[2] += a.z; acc[3] += a.w;
            acc[4] += b.x; acc[5] += b.y; acc[6] += b.z; acc[7] += b.w;
        }
        u16x8 oh, ol;
        #pragma unroll
        for (int j = 0; j < 8; ++j) {
            float m = acc[j] * (1.0f / SAMPLE);
            u16 h, lo; split_bf(m, h, lo);
            oh[j] = h; ol[j] = lo;
        }
        *(u16x8*)&agg_h[nl][fg * 8] = oh;
        *(u16x8*)&agg_l[nl][fg * 8] = ol;
    }
    __syncthreads();

    const int w  = t >> 6;
    const int l  = t & 63;
    const int lr = l & 15;
    const int lq = l >> 4;

    bf16x8 ah[4], al[4];
    #pragma unroll
    for (int k = 0; k < 4; ++k) {
        ah[k] = *(const bf16x8*)&agg_h[w * 16 + lr][k * 32 + lq * 8];
        al[k] = *(const bf16x8*)&agg_l[w * 16 + lr][k * 32 + lq * 8];
    }

    #pragma unroll
    for (int c = 0; c < 8; ++c) {
        f32x4 acc = {0.f, 0.f, 0.f, 0.f};
        #pragma unroll
        for (int k = 0; k < 4; ++k) {
            const size_t off = (size_t)(c * 16 + lr) * FEAT + k * 32 + lq * 8;
            bf16x8 bh = *(const bf16x8*)(w1h + off);
            bf16x8 bl = *(const bf16x8*)(w1l + off);
            acc = mfma_split(ah[k], al[k], bh, bl, acc);
        }
        #pragma unroll
        for (int r = 0; r < 4; ++r) {
            int node = blockStart + w * 16 + lq * 4 + r;
            if (node < N_NODES) {
                float v = acc[r] > 0.f ? acc[r] : 0.f;
                h1[(size_t)node * FEAT + c * 16 + lr] = f2bf(v);
            }
        }
    }
}

__global__ __launch_bounds__(256) void gnn_layer2_final(
    const u16* __restrict__ h1, const int* __restrict__ nb,
    const u16* __restrict__ w2h, const u16* __restrict__ w2l,
    const u16* __restrict__ wlh, const u16* __restrict__ wll,
    float* __restrict__ out)
{
    __shared__ int nbs[NPB * SAMPLE];
    __shared__ u16 agg_h[NPB][AGG_STRIDE];
    __shared__ u16 agg_l[NPB][AGG_STRIDE];

    const int t = threadIdx.x;
    const int blockStart = blockIdx.x * NPB;

    for (int i = t; i < NPB * SAMPLE; i += 256) {
        int gi = blockStart * SAMPLE + i;
        if (gi >= N_NODES * SAMPLE) gi = N_NODES * SAMPLE - 1;
        nbs[i] = nb[gi];
    }
    __syncthreads();

    for (int item = t; item < NPB * 16; item += 256) {
        const int nl = item >> 4;
        const int fg = item & 15;
        float acc[8];
        #pragma unroll
        for (int j = 0; j < 8; ++j) acc[j] = 0.f;
        const int* myn = &nbs[nl * SAMPLE];
        for (int s = 0; s < SAMPLE; ++s) {
            u16x8 v = *(const u16x8*)(h1 + (size_t)myn[s] * FEAT + fg * 8);
            #pragma unroll
            for (int j = 0; j < 8; ++j) acc[j] += bf2f(v[j]);
        }
        u16x8 oh, ol;
        #pragma unroll
        for (int j = 0; j < 8; ++j) {
            float m = acc[j] * (1.0f / SAMPLE);
            u16 h, lo; split_bf(m, h, lo);
            oh[j] = h; ol[j] = lo;
        }
        *(u16x8*)&agg_h[nl][fg * 8] = oh;
        *(u16x8*)&agg_l[nl][fg * 8] = ol;
    }
    __syncthreads();

    const int w  = t >> 6;
    const int l  = t & 63;
    const int lr = l & 15;
    const int lq = l >> 4;

    f32x4 hacc[8];
    {
        bf16x8 ah[4], al[4];
        #pragma unroll
        for (int k = 0; k < 4; ++k) {
            ah[k] = *(const bf16x8*)&agg_h[w * 16 + lr][k * 32 + lq * 8];
            al[k] = *(const bf16x8*)&agg_l[w * 16 + lr][k * 32 + lq * 8];
        }
        #pragma unroll
        for (int c = 0; c < 8; ++c) {
            f32x4 acc = {0.f, 0.f, 0.f, 0.f};
            #pragma unroll
            for (int k = 0; k < 4; ++k) {
                const size_t off = (size_t)(c * 16 + lr) * FEAT + k * 32 + lq * 8;
                bf16x8 bh = *(const bf16x8*)(w2h + off);
                bf16x8 bl = *(const bf16x8*)(w2l + off);
                acc = mfma_split(ah[k], al[k], bh, bl, acc);
            }
            hacc[c] = acc;
        }
    }
    __syncthreads();

    #pragma unroll
    for (int c = 0; c < 8; ++c) {
        #pragma unroll
        for (int r = 0; r < 4; ++r) {
            float v = hacc[c][r] > 0.f ? hacc[c][r] : 0.f;
            u16 h, l2; split_bf(v, h, l2);
            agg_h[w * 16 + lq * 4 + r][c * 16 + lr] = h;
            agg_l[w * 16 + lq * 4 + r][c * 16 + lr] = l2;
        }
    }
    __syncthreads();

    {
        bf16x8 ah[4], al[4];
        #pragma unroll
        for (int k = 0; k < 4; ++k) {
            ah[k] = *(const bf16x8*)&agg_h[w * 16 + lr][k * 32 + lq * 8];
            al[k] = *(const bf16x8*)&agg_l[w * 16 + lr][k * 32 + lq * 8];
        }
        #pragma unroll
        for (int c = 0; c < 3; ++c) {
            const int o = c * 16 + lr;
            f32x4 acc = {0.f, 0.f, 0.f, 0.f};
            #pragma unroll
            for (int k = 0; k < 4; ++k) {
                bf16x8 bh, bl;
                if (o < CLASSES) {
                    const size_t off = (size_t)o * FEAT + k * 32 + lq * 8;
                    bh = *(const bf16x8*)(wlh + off);
                    bl = *(const bf16x8*)(wll + off);
                } else {
                    #pragma unroll
                    for (int j = 0; j < 8; ++j) { bh[j] = (__bf16)0.f; bl[j] = (__bf16)0.f; }
                }
                acc = mfma_split(ah[k], al[k], bh, bl, acc);
            }
            if (o < CLASSES) {
                #pragma unroll
                for (int r = 0; r < 4; ++r) {
                    int node = blockStart + w * 16 + lq * 4 + r;
                    if (node < N_NODES) {
                        out[(size_t)node * CLASSES + o] = acc[r];
                    }
                }
            }
        }
    }
}

extern "C" void kernel_launch(void* const* d_in, const int* in_sizes, int n_in,
                              void* d_out, int out_size, void* d_ws, size_t ws_size,
                              hipStream_t stream) {
    const float* X  = (const float*)d_in[0];
    const int*   nb = (const int*)d_in[1];
    const float* W1 = (const float*)d_in[2];
    const float* W2 = (const float*)d_in[3];
    const float* Wl = (const float*)d_in[4];
    float* out = (float*)d_out;

    const size_t zelems = (size_t)N_NODES * FEAT;                 // 12.8M
    const size_t welems = 4 * (size_t)FEAT * FEAT + 2 * (size_t)CLASSES * FEAT;
    const size_t need_fast = (2 * zelems + welems) * sizeof(u16) + 64;

    if (ws_size >= need_fast) {
        u16* Xb  = (u16*)d_ws;
        u16* Z2  = Xb + zelems;
        u16* w1h = Z2 + zelems;
        u16* w1l = w1h + FEAT * FEAT;
        u16* w2h = w1l + FEAT * FEAT;
        u16* w2l = w2h + FEAT * FEAT;
        u16* wlh = w2l + FEAT * FEAT;
        u16* wll = wlh + CLASSES * FEAT;
        // counters: 8-byte aligned slot after wll
        uintptr_t cp = ((uintptr_t)(wll + CLASSES * FEAT) + 7) & ~(uintptr_t)7;
        int* ctr = (int*)cp;

        // cooperative grid size from occupancy (all blocks must be co-resident)
        static int bpc = 0;
        if (bpc == 0) {
            hipError_t oe = hipOccupancyMaxActiveBlocksPerMultiprocessor(
                &bpc, fused_all, 128, 0);
            if (oe != hipSuccess || bpc <= 0) bpc = -1;   // mark unusable
        }

        bool launched = false;
        if (bpc > 0) {
            int grid = 256 * bpc;
            if (grid > 2048) grid = 2048;
            void* args[] = {
                (void*)&X, (void*)&nb, (void*)&W1, (void*)&W2, (void*)&Wl,
                (void*)&Xb, (void*)&Z2,
                (void*)&w1h, (void*)&w1l, (void*)&w2h, (void*)&w2l,
                (void*)&wlh, (void*)&wll, (void*)&ctr, (void*)&out
            };
            hipError_t e = hipLaunchCooperativeKernel(
                (void*)fused_all, dim3(grid), dim3(128), args, 0, stream);
            launched = (e == hipSuccess);
        }

        if (!launched) {
            // proven R5 3-kernel path
            prep_all<<<512, 256, 0, stream>>>(X, W1, W2, Wl, Xb,
                                              w1h, w1l, w2h, w2l, wlh, wll);
            const int blocks = N_NODES / NPB32;  // 3125
            hopA<<<blocks, 128, 0, stream>>>(Xb, nb, w1h, w1l, w2h, w2l, Z2);
            hopB<<<blocks, 128, 0, stream>>>(Z2, nb, wlh, wll, out);
        }
    } else {
        u16* h1  = (u16*)d_ws;
        u16* w1h = h1 + zelems;
        u16* w1l = w1h + FEAT * FEAT;
        u16* w2h = w1l + FEAT * FEAT;
        u16* w2l = w2h + FEAT * FEAT;
        u16* wlh = w2l + FEAT * FEAT;
        u16* wll = wlh + CLASSES * FEAT;

        prep_all<<<512, 256, 0, stream>>>(X, W1, W2, Wl, h1,
                                          w1h, w1l, w2h, w2l, wlh, wll);
        const int blocks = (N_NODES + NPB - 1) / NPB;  // 1563
        gnn_layer1<<<blocks, 256, 0, stream>>>(X, nb, w1h, w1l, h1);
        gnn_layer2_final<<<blocks, 256, 0, stream>>>(h1, nb, w2h, w2l, wlh, wll, out);
    }
}

// Round 7
// 329.496 us; speedup vs baseline: 2.1879x; 2.1879x over previous
//
#include <hip/hip_runtime.h>
#include <cstdint>
#include <cstddef>

typedef unsigned short u16;
typedef __bf16 bf16x8 __attribute__((ext_vector_type(8)));
typedef u16 u16x8 __attribute__((ext_vector_type(8)));
typedef float f32x4 __attribute__((ext_vector_type(4)));

#define N_NODES 100000
#define SAMPLE 25
#define FEAT 128
#define CLASSES 40

__device__ __forceinline__ float bf2f(u16 v) {
    return __uint_as_float(((unsigned)v) << 16);
}
__device__ __forceinline__ u16 f2bf(float f) {
    unsigned u = __float_as_uint(f);
    u += 0x7FFFu + ((u >> 16) & 1u);
    return (u16)(u >> 16);
}
__device__ __forceinline__ void split_bf(float x, u16& hi, u16& lo) {
    hi = f2bf(x);
    lo = f2bf(x - bf2f(hi));
}

__device__ __forceinline__ void split8(const float* ap, bf16x8& ah, bf16x8& al) {
    union { u16x8 u; bf16x8 b; } H, L;
    #pragma unroll
    for (int j = 0; j < 8; ++j) {
        u16 h, lo; split_bf(ap[j], h, lo);
        H.u[j] = h; L.u[j] = lo;
    }
    ah = H.b; al = L.b;
}

// load 8 consecutive fp32 weights and split to hi/lo bf16 fragments in-register
__device__ __forceinline__ void wsplit8(const float* wp, bf16x8& bh, bf16x8& bl) {
    f32x4 a = *(const f32x4*)wp;
    f32x4 b = *(const f32x4*)(wp + 4);
    float tmp[8];
    #pragma unroll
    for (int j = 0; j < 4; ++j) { tmp[j] = a[j]; tmp[4 + j] = b[j]; }
    split8(tmp, bh, bl);
}

__device__ __forceinline__ f32x4 mfma_split(bf16x8 ah, bf16x8 al,
                                            bf16x8 bh, bf16x8 bl, f32x4 acc) {
    acc = __builtin_amdgcn_mfma_f32_16x16x32_bf16(ah, bh, acc, 0, 0, 0);
    acc = __builtin_amdgcn_mfma_f32_16x16x32_bf16(al, bh, acc, 0, 0, 0);
    acc = __builtin_amdgcn_mfma_f32_16x16x32_bf16(ah, bl, acc, 0, 0, 0);
    return acc;
}

// ===========================================================================
// FAST PATH (3 dispatches, no prep): weights split in-register at use site.
// Structure == R0 (best measured, 329 us); only the B-operand sourcing changed.
// ===========================================================================
#define NPB32 32
#define ZT_STRIDE 136

// K1: Z1 = X @ W1^T  (dense streamed GEMM, bf16 out, LDS-staged stores)
// (128,3): cap ~85 VGPR — headroom for in-reg W split (R4 lesson: (128,4)
// would cap ~64 and risk spill).
__global__ __launch_bounds__(128, 3) void k1_gemm(
    const float* __restrict__ X,
    const float* __restrict__ W1,
    u16* __restrict__ Z1)
{
    __shared__ u16 zt[NPB32][ZT_STRIDE];   // 8.7 KB

    const int t = threadIdx.x;
    const int w  = t >> 6;
    const int l  = t & 63;
    const int lr = l & 15;
    const int lq = l >> 4;
    const int blockStart = blockIdx.x * NPB32;
    const float* Xrow = X + (size_t)(blockStart + w * 16 + lr) * FEAT;

    bf16x8 ah[4], al[4];
    #pragma unroll
    for (int k = 0; k < 4; ++k) {
        f32x4 x0 = *(const f32x4*)(Xrow + k * 32 + lq * 8);
        f32x4 x1 = *(const f32x4*)(Xrow + k * 32 + lq * 8 + 4);
        float tmp[8];
        #pragma unroll
        for (int j = 0; j < 4; ++j) { tmp[j] = x0[j]; tmp[4 + j] = x1[j]; }
        split8(tmp, ah[k], al[k]);
    }

    #pragma unroll
    for (int c = 0; c < 8; ++c) {
        f32x4 acc = {0.f, 0.f, 0.f, 0.f};
        #pragma unroll
        for (int k = 0; k < 4; ++k) {
            bf16x8 bh, bl;
            wsplit8(W1 + (size_t)(c * 16 + lr) * FEAT + k * 32 + lq * 8, bh, bl);
            acc = mfma_split(ah[k], al[k], bh, bl, acc);
        }
        #pragma unroll
        for (int r = 0; r < 4; ++r)
            zt[w * 16 + lq * 4 + r][c * 16 + lr] = f2bf(acc[r]);  // no relu
    }
    __syncthreads();

    // coalesced 16B stores: 32 rows x 128 u16
    #pragma unroll
    for (int p = 0; p < 4; ++p) {
        const int idx = p * 128 + t;
        const int row = idx >> 4;
        const int col = (idx & 15) * 8;
        *(u16x8*)(Z1 + (size_t)(blockStart + row) * FEAT + col) =
            *(const u16x8*)&zt[row][col];
    }
}

// K2: h1 = relu(mean(Z1[nb])); Z2 = h1 @ W2^T (bf16, LDS-staged stores)
__global__ __launch_bounds__(128, 3) void k2_hop(
    const u16* __restrict__ Zin, const int* __restrict__ nb,
    const float* __restrict__ W2,
    u16* __restrict__ Zout)
{
    __shared__ int nbs[NPB32 * SAMPLE];
    __shared__ float agg[NPB32][132];      // 16.9 KB, reused as zt later

    const int t = threadIdx.x;
    const int blockStart = blockIdx.x * NPB32;

    for (int i = t; i < NPB32 * SAMPLE; i += 128)
        nbs[i] = nb[blockStart * SAMPLE + i];
    __syncthreads();

    // gather: burst all 25 loads into registers, then accumulate
    #pragma unroll 1
    for (int it = 0; it < 4; ++it) {
        const int item = t + it * 128;
        const int nl = item >> 4;
        const int fg = item & 15;
        const int* myn = &nbs[nl * SAMPLE];
        u16x8 buf[SAMPLE];
        #pragma unroll
        for (int s = 0; s < SAMPLE; ++s)
            buf[s] = *(const u16x8*)(Zin + ((size_t)myn[s] << 7) + fg * 8);
        float acc[8];
        #pragma unroll
        for (int j = 0; j < 8; ++j) acc[j] = 0.f;
        #pragma unroll
        for (int s = 0; s < SAMPLE; ++s) {
            #pragma unroll
            for (int j = 0; j < 8; ++j) acc[j] += bf2f(buf[s][j]);
        }
        #pragma unroll
        for (int j = 0; j < 8; ++j) {
            float m = acc[j] * (1.0f / SAMPLE);
            agg[nl][fg * 8 + j] = m > 0.f ? m : 0.f;   // relu(mean)
        }
    }
    __syncthreads();

    const int w  = t >> 6;
    const int l  = t & 63;
    const int lr = l & 15;
    const int lq = l >> 4;

    bf16x8 ah[4], al[4];
    #pragma unroll
    for (int k = 0; k < 4; ++k)
        split8(&agg[w * 16 + lr][k * 32 + lq * 8], ah[k], al[k]);
    __syncthreads();                        // A-frags in regs; agg reusable

    u16* zt = (u16*)agg;                    // [NPB32][ZT_STRIDE] u16 view

    #pragma unroll
    for (int c = 0; c < 8; ++c) {
        f32x4 acc = {0.f, 0.f, 0.f, 0.f};
        #pragma unroll
        for (int k = 0; k < 4; ++k) {
            bf16x8 bh, bl;
            wsplit8(W2 + (size_t)(c * 16 + lr) * FEAT + k * 32 + lq * 8, bh, bl);
            acc = mfma_split(ah[k], al[k], bh, bl, acc);
        }
        #pragma unroll
        for (int r = 0; r < 4; ++r)
            zt[(size_t)(w * 16 + lq * 4 + r) * ZT_STRIDE + c * 16 + lr] = f2bf(acc[r]);
    }
    __syncthreads();

    #pragma unroll
    for (int p = 0; p < 4; ++p) {
        const int idx = p * 128 + t;
        const int row = idx >> 4;
        const int col = (idx & 15) * 8;
        *(u16x8*)(Zout + (size_t)(blockStart + row) * FEAT + col) =
            *(const u16x8*)&zt[(size_t)row * ZT_STRIDE + col];
    }
}

// K3: h2 = relu(mean(Z2[nb])); out = h2 @ Wlast^T (fp32, direct stores)
__global__ __launch_bounds__(128, 3) void k3_hop(
    const u16* __restrict__ Zin, const int* __restrict__ nb,
    const float* __restrict__ Wl,
    float* __restrict__ out)
{
    __shared__ int nbs[NPB32 * SAMPLE];
    __shared__ float agg[NPB32][132];

    const int t = threadIdx.x;
    const int blockStart = blockIdx.x * NPB32;

    for (int i = t; i < NPB32 * SAMPLE; i += 128)
        nbs[i] = nb[blockStart * SAMPLE + i];
    __syncthreads();

    #pragma unroll 1
    for (int it = 0; it < 4; ++it) {
        const int item = t + it * 128;
        const int nl = item >> 4;
        const int fg = item & 15;
        const int* myn = &nbs[nl * SAMPLE];
        u16x8 buf[SAMPLE];
        #pragma unroll
        for (int s = 0; s < SAMPLE; ++s)
            buf[s] = *(const u16x8*)(Zin + ((size_t)myn[s] << 7) + fg * 8);
        float acc[8];
        #pragma unroll
        for (int j = 0; j < 8; ++j) acc[j] = 0.f;
        #pragma unroll
        for (int s = 0; s < SAMPLE; ++s) {
            #pragma unroll
            for (int j = 0; j < 8; ++j) acc[j] += bf2f(buf[s][j]);
        }
        #pragma unroll
        for (int j = 0; j < 8; ++j) {
            float m = acc[j] * (1.0f / SAMPLE);
            agg[nl][fg * 8 + j] = m > 0.f ? m : 0.f;   // relu(mean)
        }
    }
    __syncthreads();

    const int w  = t >> 6;
    const int l  = t & 63;
    const int lr = l & 15;
    const int lq = l >> 4;

    bf16x8 ah[4], al[4];
    #pragma unroll
    for (int k = 0; k < 4; ++k)
        split8(&agg[w * 16 + lr][k * 32 + lq * 8], ah[k], al[k]);

    #pragma unroll
    for (int c = 0; c < 3; ++c) {
        const int o = c * 16 + lr;
        f32x4 acc = {0.f, 0.f, 0.f, 0.f};
        #pragma unroll
        for (int k = 0; k < 4; ++k) {
            bf16x8 bh, bl;
            if (o < CLASSES) {
                wsplit8(Wl + (size_t)o * FEAT + k * 32 + lq * 8, bh, bl);
            } else {
                #pragma unroll
                for (int j = 0; j < 8; ++j) { bh[j] = (__bf16)0.f; bl[j] = (__bf16)0.f; }
            }
            acc = mfma_split(ah[k], al[k], bh, bl, acc);
        }
        if (o < CLASSES) {
            #pragma unroll
            for (int r = 0; r < 4; ++r) {
                const int node = blockStart + w * 16 + lq * 4 + r;
                out[(size_t)node * CLASSES + o] = acc[r];
            }
        }
    }
}

// ===========================================================================
// FALLBACK PATH (proven kernels, ws >= 25.9 MB only) — unchanged
// ===========================================================================
#define NPB 64
#define AGG_STRIDE 136

__global__ __launch_bounds__(256) void prep_weights(
    const float* __restrict__ W1, const float* __restrict__ W2,
    const float* __restrict__ Wl,
    u16* __restrict__ w1h, u16* __restrict__ w1l,
    u16* __restrict__ w2h, u16* __restrict__ w2l,
    u16* __restrict__ wlh, u16* __restrict__ wll)
{
    const int i = blockIdx.x * 256 + threadIdx.x;
    const int stride = gridDim.x * 256;
    for (int j = i; j < FEAT * FEAT; j += stride) {
        split_bf(W1[j], w1h[j], w1l[j]);
        split_bf(W2[j], w2h[j], w2l[j]);
    }
    for (int j = i; j < CLASSES * FEAT; j += stride) {
        split_bf(Wl[j], wlh[j], wll[j]);
    }
}

__global__ __launch_bounds__(256) void gnn_layer1(
    const float* __restrict__ X, const int* __restrict__ nb,
    const u16* __restrict__ w1h, const u16* __restrict__ w1l,
    u16* __restrict__ h1)
{
    __shared__ int nbs[NPB * SAMPLE];
    __shared__ u16 agg_h[NPB][AGG_STRIDE];
    __shared__ u16 agg_l[NPB][AGG_STRIDE];

    const int t = threadIdx.x;
    const int blockStart = blockIdx.x * NPB;

    for (int i = t; i < NPB * SAMPLE; i += 256) {
        int gi = blockStart * SAMPLE + i;
        if (gi >= N_NODES * SAMPLE) gi = N_NODES * SAMPLE - 1;
        nbs[i] = nb[gi];
    }
    __syncthreads();

    for (int item = t; item < NPB * 16; item += 256) {
        const int nl = item >> 4;
        const int fg = item & 15;
        float acc[8];
        #pragma unroll
        for (int j = 0; j < 8; ++j) acc[j] = 0.f;
        const int* myn = &nbs[nl * SAMPLE];
        for (int s = 0; s < SAMPLE; ++s) {
            const float4* p = (const float4*)(X + (size_t)myn[s] * FEAT + fg * 8);
            float4 a = p[0], b = p[1];
            acc[0] += a.x; acc[1] += a.y; acc[2] += a.z; acc[3] += a.w;
            acc[4] += b.x; acc[5] += b.y; acc[6] += b.z; acc[7] += b.w;
        }
        u16x8 oh, ol;
        #pragma unroll
        for (int j = 0; j < 8; ++j) {
            float m = acc[j] * (1.0f / SAMPLE);
            u16 h, lo; split_bf(m, h, lo);
            oh[j] = h; ol[j] = lo;
        }
        *(u16x8*)&agg_h[nl][fg * 8] = oh;
        *(u16x8*)&agg_l[nl][fg * 8] = ol;
    }
    __syncthreads();

    const int w  = t >> 6;
    const int l  = t & 63;
    const int lr = l & 15;
    const int lq = l >> 4;

    bf16x8 ah[4], al[4];
    #pragma unroll
    for (int k = 0; k < 4; ++k) {
        ah[k] = *(const bf16x8*)&agg_h[w * 16 + lr][k * 32 + lq * 8];
        al[k] = *(const bf16x8*)&agg_l[w * 16 + lr][k * 32 + lq * 8];
    }

    #pragma unroll
    for (int c = 0; c < 8; ++c) {
        f32x4 acc = {0.f, 0.f, 0.f, 0.f};
        #pragma unroll
        for (int k = 0; k < 4; ++k) {
            const size_t off = (size_t)(c * 16 + lr) * FEAT + k * 32 + lq * 8;
            bf16x8 bh = *(const bf16x8*)(w1h + off);
            bf16x8 bl = *(const bf16x8*)(w1l + off);
            acc = mfma_split(ah[k], al[k], bh, bl, acc);
        }
        #pragma unroll
        for (int r = 0; r < 4; ++r) {
            int node = blockStart + w * 16 + lq * 4 + r;
            if (node < N_NODES) {
                float v = acc[r] > 0.f ? acc[r] : 0.f;
                h1[(size_t)node * FEAT + c * 16 + lr] = f2bf(v);
            }
        }
    }
}

__global__ __launch_bounds__(256) void gnn_layer2_final(
    const u16* __restrict__ h1, const int* __restrict__ nb,
    const u16* __restrict__ w2h, const u16* __restrict__ w2l,
    const u16* __restrict__ wlh, const u16* __restrict__ wll,
    float* __restrict__ out)
{
    __shared__ int nbs[NPB * SAMPLE];
    __shared__ u16 agg_h[NPB][AGG_STRIDE];
    __shared__ u16 agg_l[NPB][AGG_STRIDE];

    const int t = threadIdx.x;
    const int blockStart = blockIdx.x * NPB;

    for (int i = t; i < NPB * SAMPLE; i += 256) {
        int gi = blockStart * SAMPLE + i;
        if (gi >= N_NODES * SAMPLE) gi = N_NODES * SAMPLE - 1;
        nbs[i] = nb[gi];
    }
    __syncthreads();

    for (int item = t; item < NPB * 16; item += 256) {
        const int nl = item >> 4;
        const int fg = item & 15;
        float acc[8];
        #pragma unroll
        for (int j = 0; j < 8; ++j) acc[j] = 0.f;
        const int* myn = &nbs[nl * SAMPLE];
        for (int s = 0; s < SAMPLE; ++s) {
            u16x8 v = *(const u16x8*)(h1 + (size_t)myn[s] * FEAT + fg * 8);
            #pragma unroll
            for (int j = 0; j < 8; ++j) acc[j] += bf2f(v[j]);
        }
        u16x8 oh, ol;
        #pragma unroll
        for (int j = 0; j < 8; ++j) {
            float m = acc[j] * (1.0f / SAMPLE);
            u16 h, lo; split_bf(m, h, lo);
            oh[j] = h; ol[j] = lo;
        }
        *(u16x8*)&agg_h[nl][fg * 8] = oh;
        *(u16x8*)&agg_l[nl][fg * 8] = ol;
    }
    __syncthreads();

    const int w  = t >> 6;
    const int l  = t & 63;
    const int lr = l & 15;
    const int lq = l >> 4;

    f32x4 hacc[8];
    {
        bf16x8 ah[4], al[4];
        #pragma unroll
        for (int k = 0; k < 4; ++k) {
            ah[k] = *(const bf16x8*)&agg_h[w * 16 + lr][k * 32 + lq * 8];
            al[k] = *(const bf16x8*)&agg_l[w * 16 + lr][k * 32 + lq * 8];
        }
        #pragma unroll
        for (int c = 0; c < 8; ++c) {
            f32x4 acc = {0.f, 0.f, 0.f, 0.f};
            #pragma unroll
            for (int k = 0; k < 4; ++k) {
                const size_t off = (size_t)(c * 16 + lr) * FEAT + k * 32 + lq * 8;
                bf16x8 bh = *(const bf16x8*)(w2h + off);
                bf16x8 bl = *(const bf16x8*)(w2l + off);
                acc = mfma_split(ah[k], al[k], bh, bl, acc);
            }
            hacc[c] = acc;
        }
    }
    __syncthreads();

    #pragma unroll
    for (int c = 0; c < 8; ++c) {
        #pragma unroll
        for (int r = 0; r < 4; ++r) {
            float v = hacc[c][r] > 0.f ? hacc[c][r] : 0.f;
            u16 h, l2; split_bf(v, h, l2);
            agg_h[w * 16 + lq * 4 + r][c * 16 + lr] = h;
            agg_l[w * 16 + lq * 4 + r][c * 16 + lr] = l2;
        }
    }
    __syncthreads();

    {
        bf16x8 ah[4], al[4];
        #pragma unroll
        for (int k = 0; k < 4; ++k) {
            ah[k] = *(const bf16x8*)&agg_h[w * 16 + lr][k * 32 + lq * 8];
            al[k] = *(const bf16x8*)&agg_l[w * 16 + lr][k * 32 + lq * 8];
        }
        #pragma unroll
        for (int c = 0; c < 3; ++c) {
            const int o = c * 16 + lr;
            f32x4 acc = {0.f, 0.f, 0.f, 0.f};
            #pragma unroll
            for (int k = 0; k < 4; ++k) {
                bf16x8 bh, bl;
                if (o < CLASSES) {
                    const size_t off = (size_t)o * FEAT + k * 32 + lq * 8;
                    bh = *(const bf16x8*)(wlh + off);
                    bl = *(const bf16x8*)(wll + off);
                } else {
                    #pragma unroll
                    for (int j = 0; j < 8; ++j) { bh[j] = (__bf16)0.f; bl[j] = (__bf16)0.f; }
                }
                acc = mfma_split(ah[k], al[k], bh, bl, acc);
            }
            if (o < CLASSES) {
                #pragma unroll
                for (int r = 0; r < 4; ++r) {
                    int node = blockStart + w * 16 + lq * 4 + r;
                    if (node < N_NODES) {
                        out[(size_t)node * CLASSES + o] = acc[r];
                    }
                }
            }
        }
    }
}

extern "C" void kernel_launch(void* const* d_in, const int* in_sizes, int n_in,
                              void* d_out, int out_size, void* d_ws, size_t ws_size,
                              hipStream_t stream) {
    const float* X  = (const float*)d_in[0];
    const int*   nb = (const int*)d_in[1];
    const float* W1 = (const float*)d_in[2];
    const float* W2 = (const float*)d_in[3];
    const float* Wl = (const float*)d_in[4];
    float* out = (float*)d_out;

    const size_t zelems = (size_t)N_NODES * FEAT;                 // 12.8M
    const size_t need_fast = 2 * zelems * sizeof(u16);            // 51.2 MB

    if (ws_size >= need_fast) {
        u16* Z1 = (u16*)d_ws;
        u16* Z2 = Z1 + zelems;

        const int blocks = N_NODES / NPB32;  // 3125, exact
        k1_gemm<<<blocks, 128, 0, stream>>>(X, W1, Z1);
        k2_hop<<<blocks, 128, 0, stream>>>(Z1, nb, W2, Z2);
        k3_hop<<<blocks, 128, 0, stream>>>(Z2, nb, Wl, out);
    } else {
        u16* h1  = (u16*)d_ws;
        u16* w1h = h1 + zelems;
        u16* w1l = w1h + FEAT * FEAT;
        u16* w2h = w1l + FEAT * FEAT;
        u16* w2l = w2h + FEAT * FEAT;
        u16* wlh = w2l + FEAT * FEAT;
        u16* wll = wlh + CLASSES * FEAT;

        prep_weights<<<64, 256, 0, stream>>>(W1, W2, Wl, w1h, w1l, w2h, w2l, wlh, wll);
        const int blocks = (N_NODES + NPB - 1) / NPB;  // 1563
        gnn_layer1<<<blocks, 256, 0, stream>>>(X, nb, w1h, w1l, h1);
        gnn_layer2_final<<<blocks, 256, 0, stream>>>(h1, nb, w2h, w2l, wlh, wll, out);
    }
}